// Round 17
// baseline (129.543 us; speedup 1.0000x reference)
//
#include <hip/hip_runtime.h>
#include <hip/hip_bf16.h>
#include <math.h>
#include <stdint.h>

typedef __hip_bfloat16 bf16;
typedef __attribute__((ext_vector_type(8))) short short8;
typedef __attribute__((ext_vector_type(4))) float f32x4;
typedef __attribute__((ext_vector_type(16))) float f32x16;

#define NB 2
#define NS 2048
#define ND 1024
#define NH 16
#define NHD 64
#define N3D 3072

// softmax scale folded into exp2 domain: (1/sqrt(64)) * log2(e)
#define SM_SCALE 0.18033688011112042f

// ---- split-K slot tables: 40 slots/bh, LPT (len-desc). ps==255 -> full tile ----
__constant__ const unsigned char S_TILE[40] = {3, 7, 7, 10, 11, 11, 11, 14, 14, 15,
                                               15, 15, 15, 6, 6, 9, 9, 10, 10, 12,
                                               12, 13, 13, 13, 13, 14, 14, 2, 5, 5,
                                               8, 8, 8, 9, 12, 12, 4, 4, 1, 0};
__constant__ const unsigned char S_C0[40] = {0, 0, 8, 0, 0, 8, 16, 0, 8, 0,
                                             8, 16, 24, 0, 7, 0, 7, 8, 15, 0,
                                             7, 0, 7, 14, 21, 16, 23, 0, 0, 6,
                                             0, 6, 12, 14, 14, 20, 0, 5, 0, 0};
__constant__ const unsigned char S_C1[40] = {8, 8, 16, 8, 8, 16, 24, 8, 16, 8,
                                             16, 24, 32, 7, 14, 7, 14, 15, 22, 7,
                                             14, 7, 14, 21, 28, 23, 30, 6, 6, 12,
                                             6, 12, 18, 20, 20, 26, 5, 10, 4, 2};
__constant__ const unsigned char S_PS[40] = {255, 6, 7, 14, 17, 18, 19, 28, 29, 32,
                                             33, 34, 35, 4, 5, 11, 12, 15, 16, 20,
                                             21, 24, 25, 26, 27, 30, 31, 255, 2, 3,
                                             8, 9, 10, 13, 22, 23, 0, 1, 255, 255};
// combine: parts base index and count per tile
__constant__ const unsigned char PS_BASE[16] = {0, 0, 0, 0, 0, 2, 4, 6, 8, 11, 14, 17, 20, 24, 28, 32};
__constant__ const unsigned char NP_TAB[16] = {1, 1, 1, 1, 2, 2, 2, 2, 3, 3, 3, 3, 4, 4, 4, 4};

// ---------------- async global->LDS, 16B per lane ----------------
__device__ __forceinline__ void gload16(const bf16* g, void* l) {
  __builtin_amdgcn_global_load_lds(
      (const __attribute__((address_space(1))) uint32_t*)g,
      (__attribute__((address_space(3))) uint32_t*)l, 16, 0, 0);
}

// ---------------- fused fp32 -> bf16 cast for x, Wqkv, Wout ----------------
__global__ void cast3_kernel(const float4* __restrict__ x, bf16* __restrict__ xb,
                             const float4* __restrict__ wq, bf16* __restrict__ wqb,
                             const float4* __restrict__ wo, bf16* __restrict__ wob) {
  int i = blockIdx.x * blockDim.x + threadIdx.x;  // 0 .. 2097152
  const float4* src;
  bf16* dst;
  int off;
  if (i < 1048576) {
    src = x; dst = xb; off = i;
  } else if (i < 1835008) {
    src = wq; dst = wqb; off = i - 1048576;
  } else {
    src = wo; dst = wob; off = i - 1835008;
  }
  float4 v = src[off];
  alignas(8) bf16 r[4];
  r[0] = __float2bfloat16(v.x);
  r[1] = __float2bfloat16(v.y);
  r[2] = __float2bfloat16(v.z);
  r[3] = __float2bfloat16(v.w);
  *reinterpret_cast<uint2*>(dst + (size_t)off * 4) = *reinterpret_cast<const uint2*>(r);
}

// ---------------- RoPE cos/sin tables: [S][32] each ----------------
__global__ void ropetab_kernel(float* __restrict__ cs_tab, float* __restrict__ sn_tab) {
  int idx = blockIdx.x * blockDim.x + threadIdx.x;  // 65536
  int j = idx & 31;
  int s = idx >> 5;
  float inv = exp2f((float)(2 * j) * (-13.287712379549449f / 64.0f));
  float ang = (float)s * inv;
  float sn, cs;
  sincosf(ang, &sn, &cs);
  cs_tab[idx] = cs;
  sn_tab[idx] = sn;
}

// ========== persistent 3-tile QKV GEMM (R15 verified) ==========
__global__ __launch_bounds__(512) void gemm_qkv(const bf16* __restrict__ Ap,
                                                const bf16* __restrict__ Bp,
                                                const float* __restrict__ cs_tab,
                                                const float* __restrict__ sn_tab,
                                                bf16* __restrict__ Qr, bf16* __restrict__ Kr,
                                                bf16* __restrict__ Vt) {
  __shared__ short L[2][32768];  // [slot][A|B0|B1|B2], each region [128][64]
  const int tid = threadIdx.x;
  const int lane = tid & 63;
  const int w = tid >> 6;
  const int wm = w >> 2, wn = w & 3;
  const int l15 = lane & 15, l4 = lane >> 4;
  const int lin = blockIdx.x;
  const int xcd = lin & 7, t2 = lin >> 3;
  const int byy = (xcd << 2) | (t2 & 3);
  const int g = t2 >> 2;
  const int bm0 = byy * 128;
  const int bn0 = g * 128;

  const int rw = lane >> 3, sg = lane & 7;
  const int swseg = (sg ^ rw) * 8;
  const int reg = w >> 1;
  const int rowb = (w & 1) * 64 + rw;
  const bf16* srcbase;
  if (reg == 0)
    srcbase = Ap + (size_t)(bm0 + rowb) * 1024 + swseg;
  else
    srcbase = Bp + (size_t)((reg - 1) * 1024 + bn0 + rowb) * 1024 + swseg;
  const int ldsb = w * 4096;

  f32x4 acc[3][4][2] = {};

  auto issue = [&](int t) {
    short* dst = &L[t & 1][ldsb];
    const bf16* s = srcbase + t * 64;
#pragma unroll
    for (int j = 0; j < 8; ++j) gload16(s + (size_t)j * 8 * 1024, dst + j * 512);
  };

  issue(0);
  asm volatile("s_waitcnt vmcnt(0)" ::: "memory");
  __builtin_amdgcn_s_barrier();

  for (int t = 0; t < 16; ++t) {
    const short* S = L[t & 1];
    if (t + 1 < 16) issue(t + 1);
#pragma unroll
    for (int kk = 0; kk < 2; ++kk) {
      short8 af[4];
#pragma unroll
      for (int mi = 0; mi < 4; ++mi) {
        int row = wm * 64 + mi * 16 + l15;
        af[mi] = *(const short8*)&S[row * 64 + (((kk * 4 + l4) ^ (row & 7)) << 3)];
      }
#pragma unroll
      for (int tt = 0; tt < 3; ++tt) {
        short8 bfr[2];
#pragma unroll
        for (int ni = 0; ni < 2; ++ni) {
          int row = (wn >> 1) * 64 + (wn & 1) * 16 + ni * 32 + l15;
          bfr[ni] = *(const short8*)&S[(1 + tt) * 8192 + row * 64 +
                                       (((kk * 4 + l4) ^ (row & 7)) << 3)];
        }
        __builtin_amdgcn_s_setprio(1);
#pragma unroll
        for (int mi = 0; mi < 4; ++mi)
#pragma unroll
          for (int ni = 0; ni < 2; ++ni)
            acc[tt][mi][ni] = __builtin_amdgcn_mfma_f32_16x16x32_bf16(
                af[mi], bfr[ni], acc[tt][mi][ni], 0, 0, 0);
        __builtin_amdgcn_s_setprio(0);
      }
    }
    if (t + 1 < 16) {
      asm volatile("s_waitcnt vmcnt(0)" ::: "memory");
      __builtin_amdgcn_s_barrier();
    }
  }

  {
    const int j = (wn & 1) * 16 + l15;
    const int hq = g * 2 + (wn >> 1);
#pragma unroll
    for (int tt = 0; tt < 2; ++tt) {
      bf16* dst = tt ? Kr : Qr;
#pragma unroll
      for (int mi = 0; mi < 4; ++mi)
#pragma unroll
        for (int r = 0; r < 4; ++r) {
          int row = bm0 + wm * 64 + mi * 16 + l4 * 4 + r;
          int b = row >> 11;
          int s = row & (NS - 1);
          float cs = cs_tab[s * 32 + j];
          float sn = sn_tab[s * 32 + j];
          float v0 = acc[tt][mi][0][r];
          float v1 = acc[tt][mi][1][r];
          size_t base = ((size_t)(b * NH + hq) * NS + s) * NHD + j;
          dst[base] = __float2bfloat16(v0 * cs - v1 * sn);
          dst[base + 32] = __float2bfloat16(v1 * cs + v0 * sn);
        }
    }
  }
  __syncthreads();
  {
    bf16* vtile = reinterpret_cast<bf16*>(&L[0][0]);  // [128 c][136 s]
#pragma unroll
    for (int mi = 0; mi < 4; ++mi)
#pragma unroll
      for (int ni = 0; ni < 2; ++ni)
#pragma unroll
        for (int r = 0; r < 4; ++r) {
          int srow = wm * 64 + mi * 16 + l4 * 4 + r;
          int c = (wn >> 1) * 64 + (wn & 1) * 16 + ni * 32 + l15;
          vtile[c * 136 + srow] = __float2bfloat16(acc[2][mi][ni][r]);
        }
    __syncthreads();
    const int b_ = bm0 >> 11;
    const int s0 = (bm0 & (NS - 1)) + (tid & 3) * 32;
    const int c = tid >> 2;
    const int head = g * 2 + (c >> 6);
    bf16* dstp = Vt + (((size_t)(b_ * NH + head)) * NHD + (c & 63)) * NS + s0;
#pragma unroll
    for (int gg = 0; gg < 4; ++gg)
      *reinterpret_cast<short8*>(dstp + gg * 8) =
          *reinterpret_cast<const short8*>(&vtile[c * 136 + (tid & 3) * 32 + gg * 8]);
  }
}

// ================= pipelined GEMM core (round-10 verified, R14 1-barrier/iter) ==========
#define GEMM_PIPE_BODY(...)                                                               \
  __shared__ short As[3][128 * 64];                                                       \
  __shared__ short Bs[3][128 * 64];                                                       \
  const int tid = threadIdx.x;                                                            \
  const int lane = tid & 63;                                                              \
  const int w = tid >> 6;                                                                 \
  const int wm = w >> 2, wn = w & 3;                                                      \
  const int l15 = lane & 15, l4 = lane >> 4;                                              \
  const int r0 = tid >> 3, seg = tid & 7;                                                 \
  const int sw = ((seg ^ (r0 & 7)) << 3);                                                 \
  const bf16* Ar0 = Ap + (size_t)(bm0 + r0) * 1024 + sw;                                  \
  const bf16* Ar1 = Ap + (size_t)(bm0 + r0 + 64) * 1024 + sw;                             \
  const bf16* Br0 = Bp + (size_t)(bn0 + r0) * 1024 + sw;                                  \
  const bf16* Br1 = Bp + (size_t)(bn0 + r0 + 64) * 1024 + sw;                             \
  f32x4 acc[4][2] = {};                                                                   \
  gload16(Ar0 + 0, &As[0][w * 512]);                                                      \
  gload16(Ar1 + 0, &As[0][4096 + w * 512]);                                               \
  gload16(Br0 + 0, &Bs[0][w * 512]);                                                      \
  gload16(Br1 + 0, &Bs[0][4096 + w * 512]);                                               \
  gload16(Ar0 + 64, &As[1][w * 512]);                                                     \
  gload16(Ar1 + 64, &As[1][4096 + w * 512]);                                              \
  gload16(Br0 + 64, &Bs[1][w * 512]);                                                     \
  gload16(Br1 + 64, &Bs[1][4096 + w * 512]);                                              \
  asm volatile("s_waitcnt vmcnt(4)" ::: "memory");                                        \
  __builtin_amdgcn_s_barrier();                                                           \
  for (int t = 0; t < 16; ++t) {                                                          \
    const int slot = t % 3;                                                               \
    if (t + 2 < 16) {                                                                     \
      const int ns = (t + 2) % 3;                                                         \
      const int nk = (t + 2) * 64;                                                        \
      gload16(Ar0 + nk, &As[ns][w * 512]);                                                \
      gload16(Ar1 + nk, &As[ns][4096 + w * 512]);                                         \
      gload16(Br0 + nk, &Bs[ns][w * 512]);                                                \
      gload16(Br1 + nk, &Bs[ns][4096 + w * 512]);                                         \
    }                                                                                     \
    _Pragma("unroll") for (int kk = 0; kk < 2; ++kk) {                                    \
      short8 af[4], bfr[2];                                                               \
      _Pragma("unroll") for (int mi = 0; mi < 4; ++mi) {                                  \
        int row = wm * 64 + mi * 16 + l15;                                                \
        af[mi] = *(const short8*)&As[slot][row * 64 + (((kk * 4 + l4) ^ (row & 7)) << 3)];\
      }                                                                                   \
      _Pragma("unroll") for (int ni = 0; ni < 2; ++ni) {                                  \
        int row = (wn >> 1) * 64 + (wn & 1) * 16 + ni * 32 + l15;                         \
        bfr[ni] = *(const short8*)&Bs[slot][row * 64 + (((kk * 4 + l4) ^ (row & 7)) << 3)];\
      }                                                                                   \
      __builtin_amdgcn_s_setprio(1);                                                      \
      _Pragma("unroll") for (int mi = 0; mi < 4; ++mi)                                    \
        _Pragma("unroll") for (int ni = 0; ni < 2; ++ni)                                  \
          acc[mi][ni] =                                                                   \
              __builtin_amdgcn_mfma_f32_16x16x32_bf16(af[mi], bfr[ni], acc[mi][ni], 0, 0, 0);\
      __builtin_amdgcn_s_setprio(0);                                                      \
    }                                                                                     \
    if (t + 2 < 16) {                                                                     \
      asm volatile("s_waitcnt vmcnt(4)" ::: "memory");                                    \
      __builtin_amdgcn_s_barrier();                                                       \
    } else if (t < 15) {                                                                  \
      asm volatile("s_waitcnt vmcnt(0)" ::: "memory");                                    \
      __builtin_amdgcn_s_barrier();                                                       \
    }                                                                                     \
  }                                                                                       \
  __VA_ARGS__

// ---------------- out-proj GEMM, M=4096 N=1024 K=1024, fp32 out ----------------
__global__ __launch_bounds__(512) void gemm_bt(const bf16* __restrict__ Ap,
                                               const bf16* __restrict__ Bp,
                                               float* __restrict__ Cv) {
  const int lin = blockIdx.x;
  const int xcd = lin & 7, idx = lin >> 3;  // 0..31
  const int bxx = (xcd & 1) * 4 + (idx & 3);
  const int byy = (xcd >> 1) * 8 + (idx >> 2);
  const int bn0 = bxx * 128, bm0 = byy * 128;
  GEMM_PIPE_BODY(
    _Pragma("unroll") for (int mi = 0; mi < 4; ++mi) {
      _Pragma("unroll") for (int ni = 0; ni < 2; ++ni) {
        _Pragma("unroll") for (int r = 0; r < 4; ++r) {
          int row = bm0 + wm * 64 + mi * 16 + l4 * 4 + r;
          int col = bn0 + (wn >> 1) * 64 + (wn & 1) * 16 + ni * 32 + l15;
          Cv[(size_t)row * ND + col] = acc[mi][ni][r];
        }
      }
    }
  )
}

// ---------------- attn_mask -> float bias ----------------
__global__ void maskbias_kernel(const int* __restrict__ amask, float* __restrict__ mb, int n) {
  int i = blockIdx.x * blockDim.x + threadIdx.x;
  if (i < n) mb[i] = amask[i] ? 0.f : -1e30f;
}

// ---------------- causal flash attention, deep split-K (parts <= 8 chunks) ----------------
// 1280 blocks = 32 bh x 40 LPT slots. Full tiles write AO; partial parts write normalized
// bf16 O + f32 (m,l), combined by combine_kernel.
__global__ __launch_bounds__(256, 2) void attn_kernel(const bf16* __restrict__ Qr,
                                                      const bf16* __restrict__ Kr,
                                                      const bf16* __restrict__ Vt,
                                                      const float* __restrict__ mb,
                                                      bf16* __restrict__ AO,
                                                      bf16* __restrict__ Opart,
                                                      float2* __restrict__ ML) {
  __shared__ short Ks[2][64 * 64];
  __shared__ short Vs[2][64 * 64];
  __shared__ float Mb[2][64];

  const int tid = threadIdx.x;
  const int lane = tid & 63;
  const int w = tid >> 6;
  const int q = lane & 31;
  const int hi = lane >> 5;

  const int lin = blockIdx.x;        // 0..1279
  const int xcd = lin & 7;
  const int k = lin >> 3;            // 0..159
  const int bh = xcd * 4 + (k & 3);
  const int slot = k >> 2;           // 0..39
  const int tile = S_TILE[slot];
  const int c0 = S_C0[slot];
  const int c1 = S_C1[slot];
  const int ps = S_PS[slot];         // 255 = full
  const int b = bh >> 4, h = bh & 15;
  const int qw = tile * 128 + w * 32;

  const bf16* Qb = Qr + (size_t)bh * NS * NHD;
  const bf16* Kb = Kr + (size_t)bh * NS * NHD;
  const bf16* Vb = Vt + (size_t)bh * NHD * NS;

  const int srow = tid >> 2;
  const int sc0 = (tid & 3) * 16;
  const int swz = (srow & 7) << 3;

  short8 Qf[4];
#pragma unroll
  for (int s = 0; s < 4; ++s)
    Qf[s] = *reinterpret_cast<const short8*>(&Qb[(size_t)(qw + q) * NHD + s * 16 + hi * 8]);

  f32x16 o0 = {}, o1 = {};
  float mx = -1e30f, lsum = 0.f;

  short8 kreg[2], vreg[2];
  float4 mreg;
  auto prefetch = [&](int kv0) {
    kreg[0] = *reinterpret_cast<const short8*>(&Kb[(size_t)(kv0 + srow) * NHD + sc0]);
    kreg[1] = *reinterpret_cast<const short8*>(&Kb[(size_t)(kv0 + srow) * NHD + sc0 + 8]);
    vreg[0] = *reinterpret_cast<const short8*>(&Vb[(size_t)srow * NS + kv0 + sc0]);
    vreg[1] = *reinterpret_cast<const short8*>(&Vb[(size_t)srow * NS + kv0 + sc0 + 8]);
    if (tid < 16) mreg = *reinterpret_cast<const float4*>(&mb[b * NS + kv0 + tid * 4]);
  };
  auto stage = [&](int buf) {
    *reinterpret_cast<short8*>(&Ks[buf][srow * 64 + (sc0 ^ swz)]) = kreg[0];
    *reinterpret_cast<short8*>(&Ks[buf][srow * 64 + ((sc0 + 8) ^ swz)]) = kreg[1];
    *reinterpret_cast<short8*>(&Vs[buf][srow * 64 + (sc0 ^ swz)]) = vreg[0];
    *reinterpret_cast<short8*>(&Vs[buf][srow * 64 + ((sc0 + 8) ^ swz)]) = vreg[1];
    if (tid < 16) *reinterpret_cast<float4*>(&Mb[buf][tid * 4]) = mreg;
  };

  prefetch(c0 * 64);
  stage(0);
  __syncthreads();

  const int rsw = (q & 7) << 3;

  for (int c = c0; c < c1; ++c) {
    const int cur = (c - c0) & 1;
    const int kv0 = c * 64;
    if (c + 1 < c1) prefetch((c + 1) * 64);

    if (kv0 < qw + 32) {
      f32x16 a0 = {}, a1 = {};
#pragma unroll
      for (int s = 0; s < 4; ++s) {
        short8 kf0 = *reinterpret_cast<const short8*>(
            &Ks[cur][q * 64 + ((s * 16 + hi * 8) ^ rsw)]);
        short8 kf1 = *reinterpret_cast<const short8*>(
            &Ks[cur][(32 + q) * 64 + ((s * 16 + hi * 8) ^ rsw)]);
        a0 = __builtin_amdgcn_mfma_f32_32x32x16_bf16(kf0, Qf[s], a0, 0, 0, 0);
        a1 = __builtin_amdgcn_mfma_f32_32x32x16_bf16(kf1, Qf[s], a1, 0, 0, 0);
      }

      float4 bv[2][4];
#pragma unroll
      for (int t = 0; t < 2; ++t)
#pragma unroll
        for (int g = 0; g < 4; ++g)
          bv[t][g] = *reinterpret_cast<const float4*>(&Mb[cur][t * 32 + g * 8 + hi * 4]);
      const int qg = qw + q;
#pragma unroll
      for (int t = 0; t < 2; ++t) {
        f32x16& a = t ? a1 : a0;
        const bool needc = (kv0 + t * 32 + 31 > qw);
#pragma unroll
        for (int r = 0; r < 16; ++r) {
          float v = fmaf(a[r], SM_SCALE, ((const float*)&bv[t][r >> 2])[r & 3]);
          if (needc) {
            int kvg = kv0 + t * 32 + (r & 3) + 8 * (r >> 2) + 4 * hi;
            if (kvg > qg) v = -1e30f;
          }
          a[r] = v;
        }
      }

      float cm = a0[0];
#pragma unroll
      for (int r = 1; r < 16; ++r) cm = fmaxf(cm, a0[r]);
#pragma unroll
      for (int r = 0; r < 16; ++r) cm = fmaxf(cm, a1[r]);
      float pm = fmaxf(cm, __shfl_xor(cm, 32));

      if (!__all(pm <= mx + 8.f)) {
        float mn = fmaxf(mx, pm);
        float fac = __builtin_amdgcn_exp2f(mx - mn);
        mx = mn;
        lsum *= fac;
#pragma unroll
        for (int r = 0; r < 16; ++r) {
          float fq = __shfl(fac, (r & 3) + 8 * (r >> 2) + 4 * hi);
          o0[r] *= fq;
          o1[r] *= fq;
        }
      }

      float rs = 0.f;
      short8 pa[4];
#pragma unroll
      for (int t = 0; t < 2; ++t) {
        f32x16& a = t ? a1 : a0;
#pragma unroll
        for (int r = 0; r < 16; ++r) {
          float e = __builtin_amdgcn_exp2f(a[r] - mx);
          a[r] = e;
          rs += e;
        }
#pragma unroll
        for (int g = 0; g < 2; ++g) {
          union { unsigned int u; __hip_bfloat162 h2; } X, X2, Y, Y2;
          X.h2 = __float22bfloat162_rn(float2{a[g * 8 + 0], a[g * 8 + 1]});
          X2.h2 = __float22bfloat162_rn(float2{a[g * 8 + 2], a[g * 8 + 3]});
          Y.h2 = __float22bfloat162_rn(float2{a[g * 8 + 4], a[g * 8 + 5]});
          Y2.h2 = __float22bfloat162_rn(float2{a[g * 8 + 6], a[g * 8 + 7]});
          asm volatile("v_permlane32_swap_b32 %0, %1" : "+v"(X.u), "+v"(Y.u));
          asm volatile("v_permlane32_swap_b32 %0, %1" : "+v"(X2.u), "+v"(Y2.u));
          union { unsigned int u[4]; short8 s; } P;
          P.u[0] = X.u;
          P.u[1] = X2.u;
          P.u[2] = Y.u;
          P.u[3] = Y2.u;
          pa[t * 2 + g] = P.s;
        }
      }
      lsum += rs + __shfl_xor(rs, 32);

#pragma unroll
      for (int ks = 0; ks < 4; ++ks) {
        const int vcol = (ks * 16 + hi * 8) ^ rsw;
        short8 vf0 = *reinterpret_cast<const short8*>(&Vs[cur][q * 64 + vcol]);
        short8 vf1 = *reinterpret_cast<const short8*>(&Vs[cur][(32 + q) * 64 + vcol]);
        o0 = __builtin_amdgcn_mfma_f32_32x32x16_bf16(pa[ks], vf0, o0, 0, 0, 0);
        o1 = __builtin_amdgcn_mfma_f32_32x32x16_bf16(pa[ks], vf1, o1, 0, 0, 0);
      }
    }

    if (c + 1 < c1) stage(cur ^ 1);
    __syncthreads();
  }

  float inv = 1.0f / lsum;
  if (ps == 255) {
#pragma unroll
    for (int r = 0; r < 16; ++r) {
      const int crow = (r & 3) + 8 * (r >> 2) + 4 * hi;
      float iq = __shfl(inv, crow);
      size_t base = (size_t)(b * NS + qw + crow) * ND + h * NHD;
      AO[base + q] = __float2bfloat16(o0[r] * iq);
      AO[base + 32 + q] = __float2bfloat16(o1[r] * iq);
    }
  } else {
    bf16* Ob = Opart + ((size_t)(ps * 32 + bh) * 128) * 64;
    if (hi == 0) ML[(ps * 32 + bh) * 128 + w * 32 + q] = float2{mx, lsum};
#pragma unroll
    for (int r = 0; r < 16; ++r) {
      const int crow = (r & 3) + 8 * (r >> 2) + 4 * hi;
      float iq = __shfl(inv, crow);
      Ob[(w * 32 + crow) * 64 + q] = __float2bfloat16(o0[r] * iq);
      Ob[(w * 32 + crow) * 64 + 32 + q] = __float2bfloat16(o1[r] * iq);
    }
  }
}

// ---------------- split-K combine: weighted merge of np parts -> AO ----------------
__global__ __launch_bounds__(256) void combine_kernel(const bf16* __restrict__ Opart,
                                                      const float2* __restrict__ ML,
                                                      bf16* __restrict__ AO) {
  const int bx = blockIdx.x;  // 0..383 (tiles 4..15 x 32 bh)
  const int tile = 4 + (bx >> 5);
  const int bh = bx & 31;
  const int b = bh >> 4, h = bh & 15;
  const int np = NP_TAB[tile];
  const int pb = PS_BASE[tile];
  const int row = threadIdx.x >> 1;
  const int ch = (threadIdx.x & 1) * 32;

  float mm = -1e30f;
  float2 ml[4];
  for (int i = 0; i < np; ++i) {
    ml[i] = ML[((pb + i) * 32 + bh) * 128 + row];
    mm = fmaxf(mm, ml[i].x);
  }
  float wgt[4];
  float wsum = 0.f;
  for (int i = 0; i < np; ++i) {
    wgt[i] = ml[i].y * exp2f(ml[i].x - mm);
    wsum += wgt[i];
  }
  float invw = 1.0f / wsum;

  float acc[32] = {};
  for (int i = 0; i < np; ++i) {
    const bf16* Op = Opart + ((size_t)((pb + i) * 32 + bh) * 128 + row) * 64 + ch;
    float wi = wgt[i] * invw;
#pragma unroll
    for (int g = 0; g < 4; ++g) {
      short8 v = *reinterpret_cast<const short8*>(Op + g * 8);
#pragma unroll
      for (int e = 0; e < 8; ++e) {
        unsigned int u = ((unsigned int)(unsigned short)v[e]) << 16;
        acc[g * 8 + e] += wi * __uint_as_float(u);
      }
    }
  }
  bf16* dst = AO + (size_t)(b * NS + tile * 128 + row) * ND + h * NHD + ch;
#pragma unroll
  for (int g = 0; g < 4; ++g) {
    alignas(16) bf16 rr[8];
#pragma unroll
    for (int e = 0; e < 8; ++e) rr[e] = __float2bfloat16(acc[g * 8 + e]);
    *reinterpret_cast<short8*>(dst + g * 8) = *reinterpret_cast<const short8*>(rr);
  }
}

extern "C" void kernel_launch(void* const* d_in, const int* in_sizes, int n_in,
                              void* d_out, int out_size, void* d_ws, size_t ws_size,
                              hipStream_t stream) {
  const float* x = (const float*)d_in[0];
  const int* amask = (const int*)d_in[1];
  const float* Wqkv = (const float*)d_in[2];
  const float* Wout = (const float*)d_in[3];
  float* out = (float*)d_out;

  char* p = (char*)d_ws;
  bf16* xb = (bf16*)(p);                  // 0 .. 8,388,608 (AO aliases after gemm_qkv)
  bf16* wqkvb = (bf16*)(p + 8388608);     // 8,388,608 .. 14,680,064 (dead after gemm_qkv)
  float* mbias = (float*)(p + 8388608);   //   reuse: 16,384 bytes
  float2* ML = (float2*)(p + 8404992);    //   reuse: 1,179,648 -> 9,584,640
  bf16* woutb = (bf16*)(p + 14680064);    // 2,097,152 -> 16,777,216
  bf16* Opart = (bf16*)(p + 16777216);    // 18,874,368 -> 35,651,584 (after gemm_qkv)
  float* cs_tab = (float*)(p + 25165824); // 262,144 (live only during gemm_qkv)
  float* sn_tab = (float*)(p + 25427968); // 262,144 (live only during gemm_qkv)
  bf16* Qr = (bf16*)(p + 41943040);       // 8,388,608
  bf16* Kr = (bf16*)(p + 50331648);       // 8,388,608
  bf16* Vt = (bf16*)(p + 58720256);       // 8,388,608 -> 67,108,864 end
  bf16* AO = xb;

  cast3_kernel<<<8192, 256, 0, stream>>>((const float4*)x, xb, (const float4*)Wqkv, wqkvb,
                                         (const float4*)Wout, woutb);
  ropetab_kernel<<<256, 256, 0, stream>>>(cs_tab, sn_tab);

  gemm_qkv<<<256, 512, 0, stream>>>(xb, wqkvb, cs_tab, sn_tab, Qr, Kr, Vt);
  maskbias_kernel<<<16, 256, 0, stream>>>(amask, mbias, NB * NS);
  attn_kernel<<<1280, 256, 0, stream>>>(Qr, Kr, Vt, mbias, AO, Opart, ML);
  combine_kernel<<<384, 256, 0, stream>>>(Opart, ML, AO);
  gemm_bt<<<256, 512, 0, stream>>>(AO, woutb, out);
}

// Round 18
// 113.047 us; speedup vs baseline: 1.1459x; 1.1459x over previous
//
#include <hip/hip_runtime.h>
#include <hip/hip_bf16.h>
#include <math.h>
#include <stdint.h>

typedef __hip_bfloat16 bf16;
typedef __attribute__((ext_vector_type(8))) short short8;
typedef __attribute__((ext_vector_type(4))) float f32x4;
typedef __attribute__((ext_vector_type(16))) float f32x16;

#define NB 2
#define NS 2048
#define ND 1024
#define NH 16
#define NHD 64
#define N3D 3072

// softmax scale folded into exp2 domain: (1/sqrt(64)) * log2(e)
#define SM_SCALE 0.18033688011112042f

// split-K slot table (R16 verified): 24 slots/bh, LPT order.
// mode: 0=full tile, 1=part0 (kv [0, t+1) chunks), 2=part1 (kv [t+1, 2t+2))
__constant__ const unsigned char SLOT_TILE[24] = {15, 15, 7, 14, 14, 13, 13, 6,
                                                  12, 12, 11, 11, 5, 10, 10, 9,
                                                  9,  4,  8,  8,  3, 2,  1,  0};
__constant__ const unsigned char SLOT_MODE[24] = {1, 2, 0, 1, 2, 1, 2, 0, 1, 2, 1, 2,
                                                  0, 1, 2, 1, 2, 0, 1, 2, 0, 0, 0, 0};

// ---------------- async global->LDS, 16B per lane ----------------
__device__ __forceinline__ void gload16(const bf16* g, void* l) {
  __builtin_amdgcn_global_load_lds(
      (const __attribute__((address_space(1))) uint32_t*)g,
      (__attribute__((address_space(3))) uint32_t*)l, 16, 0, 0);
}

// ---------------- fused prelude: casts + rope tables + mask bias ----------------
// blocks [0,8192): fp32->bf16 casts of x/Wqkv/Wout; [8192,8448): rope tables;
// [8448,8464): attn_mask -> float bias. All independent elementwise jobs.
__global__ void prelude_kernel(const float4* __restrict__ x, bf16* __restrict__ xb,
                               const float4* __restrict__ wq, bf16* __restrict__ wqb,
                               const float4* __restrict__ wo, bf16* __restrict__ wob,
                               float* __restrict__ cs_tab, float* __restrict__ sn_tab,
                               const int* __restrict__ amask, float* __restrict__ mbias) {
  const int blk = blockIdx.x;
  if (blk < 8192) {
    int i = blk * 256 + threadIdx.x;
    const float4* src;
    bf16* dst;
    int off;
    if (i < 1048576) {
      src = x; dst = xb; off = i;
    } else if (i < 1835008) {
      src = wq; dst = wqb; off = i - 1048576;
    } else {
      src = wo; dst = wob; off = i - 1835008;
    }
    float4 v = src[off];
    alignas(8) bf16 r[4];
    r[0] = __float2bfloat16(v.x);
    r[1] = __float2bfloat16(v.y);
    r[2] = __float2bfloat16(v.z);
    r[3] = __float2bfloat16(v.w);
    *reinterpret_cast<uint2*>(dst + (size_t)off * 4) = *reinterpret_cast<const uint2*>(r);
  } else if (blk < 8448) {
    int idx = (blk - 8192) * 256 + threadIdx.x;  // 65536
    int j = idx & 31;
    int s = idx >> 5;
    float inv = exp2f((float)(2 * j) * (-13.287712379549449f / 64.0f));
    float ang = (float)s * inv;
    float sn, cs;
    sincosf(ang, &sn, &cs);
    cs_tab[idx] = cs;
    sn_tab[idx] = sn;
  } else {
    int i = (blk - 8448) * 256 + threadIdx.x;  // 4096
    mbias[i] = amask[i] ? 0.f : -1e30f;
  }
}

// ========== persistent 3-tile QKV GEMM (R15 verified) ==========
__global__ __launch_bounds__(512) void gemm_qkv(const bf16* __restrict__ Ap,
                                                const bf16* __restrict__ Bp,
                                                const float* __restrict__ cs_tab,
                                                const float* __restrict__ sn_tab,
                                                bf16* __restrict__ Qr, bf16* __restrict__ Kr,
                                                bf16* __restrict__ Vt) {
  __shared__ short L[2][32768];  // [slot][A|B0|B1|B2], each region [128][64]
  const int tid = threadIdx.x;
  const int lane = tid & 63;
  const int w = tid >> 6;
  const int wm = w >> 2, wn = w & 3;
  const int l15 = lane & 15, l4 = lane >> 4;
  const int lin = blockIdx.x;
  const int xcd = lin & 7, t2 = lin >> 3;
  const int byy = (xcd << 2) | (t2 & 3);
  const int g = t2 >> 2;
  const int bm0 = byy * 128;
  const int bn0 = g * 128;

  const int rw = lane >> 3, sg = lane & 7;
  const int swseg = (sg ^ rw) * 8;
  const int reg = w >> 1;
  const int rowb = (w & 1) * 64 + rw;
  const bf16* srcbase;
  if (reg == 0)
    srcbase = Ap + (size_t)(bm0 + rowb) * 1024 + swseg;
  else
    srcbase = Bp + (size_t)((reg - 1) * 1024 + bn0 + rowb) * 1024 + swseg;
  const int ldsb = w * 4096;

  f32x4 acc[3][4][2] = {};

  auto issue = [&](int t) {
    short* dst = &L[t & 1][ldsb];
    const bf16* s = srcbase + t * 64;
#pragma unroll
    for (int j = 0; j < 8; ++j) gload16(s + (size_t)j * 8 * 1024, dst + j * 512);
  };

  issue(0);
  asm volatile("s_waitcnt vmcnt(0)" ::: "memory");
  __builtin_amdgcn_s_barrier();

  for (int t = 0; t < 16; ++t) {
    const short* S = L[t & 1];
    if (t + 1 < 16) issue(t + 1);
#pragma unroll
    for (int kk = 0; kk < 2; ++kk) {
      short8 af[4];
#pragma unroll
      for (int mi = 0; mi < 4; ++mi) {
        int row = wm * 64 + mi * 16 + l15;
        af[mi] = *(const short8*)&S[row * 64 + (((kk * 4 + l4) ^ (row & 7)) << 3)];
      }
#pragma unroll
      for (int tt = 0; tt < 3; ++tt) {
        short8 bfr[2];
#pragma unroll
        for (int ni = 0; ni < 2; ++ni) {
          int row = (wn >> 1) * 64 + (wn & 1) * 16 + ni * 32 + l15;
          bfr[ni] = *(const short8*)&S[(1 + tt) * 8192 + row * 64 +
                                       (((kk * 4 + l4) ^ (row & 7)) << 3)];
        }
        __builtin_amdgcn_s_setprio(1);
#pragma unroll
        for (int mi = 0; mi < 4; ++mi)
#pragma unroll
          for (int ni = 0; ni < 2; ++ni)
            acc[tt][mi][ni] = __builtin_amdgcn_mfma_f32_16x16x32_bf16(
                af[mi], bfr[ni], acc[tt][mi][ni], 0, 0, 0);
        __builtin_amdgcn_s_setprio(0);
      }
    }
    if (t + 1 < 16) {
      asm volatile("s_waitcnt vmcnt(0)" ::: "memory");
      __builtin_amdgcn_s_barrier();
    }
  }

  {
    const int j = (wn & 1) * 16 + l15;
    const int hq = g * 2 + (wn >> 1);
#pragma unroll
    for (int tt = 0; tt < 2; ++tt) {
      bf16* dst = tt ? Kr : Qr;
#pragma unroll
      for (int mi = 0; mi < 4; ++mi)
#pragma unroll
        for (int r = 0; r < 4; ++r) {
          int row = bm0 + wm * 64 + mi * 16 + l4 * 4 + r;
          int b = row >> 11;
          int s = row & (NS - 1);
          float cs = cs_tab[s * 32 + j];
          float sn = sn_tab[s * 32 + j];
          float v0 = acc[tt][mi][0][r];
          float v1 = acc[tt][mi][1][r];
          size_t base = ((size_t)(b * NH + hq) * NS + s) * NHD + j;
          dst[base] = __float2bfloat16(v0 * cs - v1 * sn);
          dst[base + 32] = __float2bfloat16(v1 * cs + v0 * sn);
        }
    }
  }
  __syncthreads();
  {
    bf16* vtile = reinterpret_cast<bf16*>(&L[0][0]);  // [128 c][136 s]
#pragma unroll
    for (int mi = 0; mi < 4; ++mi)
#pragma unroll
      for (int ni = 0; ni < 2; ++ni)
#pragma unroll
        for (int r = 0; r < 4; ++r) {
          int srow = wm * 64 + mi * 16 + l4 * 4 + r;
          int c = (wn >> 1) * 64 + (wn & 1) * 16 + ni * 32 + l15;
          vtile[c * 136 + srow] = __float2bfloat16(acc[2][mi][ni][r]);
        }
    __syncthreads();
    const int b_ = bm0 >> 11;
    const int s0 = (bm0 & (NS - 1)) + (tid & 3) * 32;
    const int c = tid >> 2;
    const int head = g * 2 + (c >> 6);
    bf16* dstp = Vt + (((size_t)(b_ * NH + head)) * NHD + (c & 63)) * NS + s0;
#pragma unroll
    for (int gg = 0; gg < 4; ++gg)
      *reinterpret_cast<short8*>(dstp + gg * 8) =
          *reinterpret_cast<const short8*>(&vtile[c * 136 + (tid & 3) * 32 + gg * 8]);
  }
}

// ================= pipelined GEMM core (round-10 verified, R14 1-barrier/iter) ==========
#define GEMM_PIPE_BODY(...)                                                               \
  __shared__ short As[3][128 * 64];                                                       \
  __shared__ short Bs[3][128 * 64];                                                       \
  const int tid = threadIdx.x;                                                            \
  const int lane = tid & 63;                                                              \
  const int w = tid >> 6;                                                                 \
  const int wm = w >> 2, wn = w & 3;                                                      \
  const int l15 = lane & 15, l4 = lane >> 4;                                              \
  const int r0 = tid >> 3, seg = tid & 7;                                                 \
  const int sw = ((seg ^ (r0 & 7)) << 3);                                                 \
  const bf16* Ar0 = Ap + (size_t)(bm0 + r0) * 1024 + sw;                                  \
  const bf16* Ar1 = Ap + (size_t)(bm0 + r0 + 64) * 1024 + sw;                             \
  const bf16* Br0 = Bp + (size_t)(bn0 + r0) * 1024 + sw;                                  \
  const bf16* Br1 = Bp + (size_t)(bn0 + r0 + 64) * 1024 + sw;                             \
  f32x4 acc[4][2] = {};                                                                   \
  gload16(Ar0 + 0, &As[0][w * 512]);                                                      \
  gload16(Ar1 + 0, &As[0][4096 + w * 512]);                                               \
  gload16(Br0 + 0, &Bs[0][w * 512]);                                                      \
  gload16(Br1 + 0, &Bs[0][4096 + w * 512]);                                               \
  gload16(Ar0 + 64, &As[1][w * 512]);                                                     \
  gload16(Ar1 + 64, &As[1][4096 + w * 512]);                                              \
  gload16(Br0 + 64, &Bs[1][w * 512]);                                                     \
  gload16(Br1 + 64, &Bs[1][4096 + w * 512]);                                              \
  asm volatile("s_waitcnt vmcnt(4)" ::: "memory");                                        \
  __builtin_amdgcn_s_barrier();                                                           \
  for (int t = 0; t < 16; ++t) {                                                          \
    const int slot = t % 3;                                                               \
    if (t + 2 < 16) {                                                                     \
      const int ns = (t + 2) % 3;                                                         \
      const int nk = (t + 2) * 64;                                                        \
      gload16(Ar0 + nk, &As[ns][w * 512]);                                                \
      gload16(Ar1 + nk, &As[ns][4096 + w * 512]);                                         \
      gload16(Br0 + nk, &Bs[ns][w * 512]);                                                \
      gload16(Br1 + nk, &Bs[ns][4096 + w * 512]);                                         \
    }                                                                                     \
    _Pragma("unroll") for (int kk = 0; kk < 2; ++kk) {                                    \
      short8 af[4], bfr[2];                                                               \
      _Pragma("unroll") for (int mi = 0; mi < 4; ++mi) {                                  \
        int row = wm * 64 + mi * 16 + l15;                                                \
        af[mi] = *(const short8*)&As[slot][row * 64 + (((kk * 4 + l4) ^ (row & 7)) << 3)];\
      }                                                                                   \
      _Pragma("unroll") for (int ni = 0; ni < 2; ++ni) {                                  \
        int row = (wn >> 1) * 64 + (wn & 1) * 16 + ni * 32 + l15;                         \
        bfr[ni] = *(const short8*)&Bs[slot][row * 64 + (((kk * 4 + l4) ^ (row & 7)) << 3)];\
      }                                                                                   \
      __builtin_amdgcn_s_setprio(1);                                                      \
      _Pragma("unroll") for (int mi = 0; mi < 4; ++mi)                                    \
        _Pragma("unroll") for (int ni = 0; ni < 2; ++ni)                                  \
          acc[mi][ni] =                                                                   \
              __builtin_amdgcn_mfma_f32_16x16x32_bf16(af[mi], bfr[ni], acc[mi][ni], 0, 0, 0);\
      __builtin_amdgcn_s_setprio(0);                                                      \
    }                                                                                     \
    if (t + 2 < 16) {                                                                     \
      asm volatile("s_waitcnt vmcnt(4)" ::: "memory");                                    \
      __builtin_amdgcn_s_barrier();                                                       \
    } else if (t < 15) {                                                                  \
      asm volatile("s_waitcnt vmcnt(0)" ::: "memory");                                    \
      __builtin_amdgcn_s_barrier();                                                       \
    }                                                                                     \
  }                                                                                       \
  __VA_ARGS__

// ---------------- out-proj GEMM, M=4096 N=1024 K=1024, fp32 out ----------------
__global__ __launch_bounds__(512) void gemm_bt(const bf16* __restrict__ Ap,
                                               const bf16* __restrict__ Bp,
                                               float* __restrict__ Cv) {
  const int lin = blockIdx.x;
  const int xcd = lin & 7, idx = lin >> 3;  // 0..31
  const int bxx = (xcd & 1) * 4 + (idx & 3);
  const int byy = (xcd >> 1) * 8 + (idx >> 2);
  const int bn0 = bxx * 128, bm0 = byy * 128;
  GEMM_PIPE_BODY(
    _Pragma("unroll") for (int mi = 0; mi < 4; ++mi) {
      _Pragma("unroll") for (int ni = 0; ni < 2; ++ni) {
        _Pragma("unroll") for (int r = 0; r < 4; ++r) {
          int row = bm0 + wm * 64 + mi * 16 + l4 * 4 + r;
          int col = bn0 + (wn >> 1) * 64 + (wn & 1) * 16 + ni * 32 + l15;
          Cv[(size_t)row * ND + col] = acc[mi][ni][r];
        }
      }
    }
  )
}

// ---------------- causal flash attention, split-K over long tiles (R16 verified) --------
__global__ __launch_bounds__(256, 2) void attn_kernel(const bf16* __restrict__ Qr,
                                                      const bf16* __restrict__ Kr,
                                                      const bf16* __restrict__ Vt,
                                                      const float* __restrict__ mb,
                                                      bf16* __restrict__ AO,
                                                      float* __restrict__ Opart,
                                                      float2* __restrict__ ML) {
  __shared__ short Ks[2][64 * 64];
  __shared__ short Vs[2][64 * 64];
  __shared__ float Mb[2][64];

  const int tid = threadIdx.x;
  const int lane = tid & 63;
  const int w = tid >> 6;
  const int q = lane & 31;
  const int hi = lane >> 5;

  const int lin = blockIdx.x;
  const int xcd = lin & 7;
  const int k = lin >> 3;           // 0..95
  const int bh = xcd * 4 + (k & 3);
  const int slot = k >> 2;          // 0..23
  const int tile = SLOT_TILE[slot];
  const int mode = SLOT_MODE[slot];
  const int b = bh >> 4, h = bh & 15;
  const int qw = tile * 128 + w * 32;
  const int c0 = (mode == 2) ? tile + 1 : 0;
  const int c1 = (mode == 1) ? tile + 1 : 2 * tile + 2;

  const bf16* Qb = Qr + (size_t)bh * NS * NHD;
  const bf16* Kb = Kr + (size_t)bh * NS * NHD;
  const bf16* Vb = Vt + (size_t)bh * NHD * NS;

  const int srow = tid >> 2;
  const int sc0 = (tid & 3) * 16;
  const int swz = (srow & 7) << 3;

  short8 Qf[4];
#pragma unroll
  for (int s = 0; s < 4; ++s)
    Qf[s] = *reinterpret_cast<const short8*>(&Qb[(size_t)(qw + q) * NHD + s * 16 + hi * 8]);

  f32x16 o0 = {}, o1 = {};
  float mx = -1e30f, lsum = 0.f;

  short8 kreg[2], vreg[2];
  float4 mreg;
  auto prefetch = [&](int kv0) {
    kreg[0] = *reinterpret_cast<const short8*>(&Kb[(size_t)(kv0 + srow) * NHD + sc0]);
    kreg[1] = *reinterpret_cast<const short8*>(&Kb[(size_t)(kv0 + srow) * NHD + sc0 + 8]);
    vreg[0] = *reinterpret_cast<const short8*>(&Vb[(size_t)srow * NS + kv0 + sc0]);
    vreg[1] = *reinterpret_cast<const short8*>(&Vb[(size_t)srow * NS + kv0 + sc0 + 8]);
    if (tid < 16) mreg = *reinterpret_cast<const float4*>(&mb[b * NS + kv0 + tid * 4]);
  };
  auto stage = [&](int buf) {
    *reinterpret_cast<short8*>(&Ks[buf][srow * 64 + (sc0 ^ swz)]) = kreg[0];
    *reinterpret_cast<short8*>(&Ks[buf][srow * 64 + ((sc0 + 8) ^ swz)]) = kreg[1];
    *reinterpret_cast<short8*>(&Vs[buf][srow * 64 + (sc0 ^ swz)]) = vreg[0];
    *reinterpret_cast<short8*>(&Vs[buf][srow * 64 + ((sc0 + 8) ^ swz)]) = vreg[1];
    if (tid < 16) *reinterpret_cast<float4*>(&Mb[buf][tid * 4]) = mreg;
  };

  prefetch(c0 * 64);
  stage(0);
  __syncthreads();

  const int rsw = (q & 7) << 3;

  for (int c = c0; c < c1; ++c) {
    const int cur = (c - c0) & 1;
    const int kv0 = c * 64;
    if (c + 1 < c1) prefetch((c + 1) * 64);

    if (kv0 < qw + 32) {
      f32x16 a0 = {}, a1 = {};
#pragma unroll
      for (int s = 0; s < 4; ++s) {
        short8 kf0 = *reinterpret_cast<const short8*>(
            &Ks[cur][q * 64 + ((s * 16 + hi * 8) ^ rsw)]);
        short8 kf1 = *reinterpret_cast<const short8*>(
            &Ks[cur][(32 + q) * 64 + ((s * 16 + hi * 8) ^ rsw)]);
        a0 = __builtin_amdgcn_mfma_f32_32x32x16_bf16(kf0, Qf[s], a0, 0, 0, 0);
        a1 = __builtin_amdgcn_mfma_f32_32x32x16_bf16(kf1, Qf[s], a1, 0, 0, 0);
      }

      float4 bv[2][4];
#pragma unroll
      for (int t = 0; t < 2; ++t)
#pragma unroll
        for (int g = 0; g < 4; ++g)
          bv[t][g] = *reinterpret_cast<const float4*>(&Mb[cur][t * 32 + g * 8 + hi * 4]);
      const int qg = qw + q;
#pragma unroll
      for (int t = 0; t < 2; ++t) {
        f32x16& a = t ? a1 : a0;
        const bool needc = (kv0 + t * 32 + 31 > qw);
#pragma unroll
        for (int r = 0; r < 16; ++r) {
          float v = fmaf(a[r], SM_SCALE, ((const float*)&bv[t][r >> 2])[r & 3]);
          if (needc) {
            int kvg = kv0 + t * 32 + (r & 3) + 8 * (r >> 2) + 4 * hi;
            if (kvg > qg) v = -1e30f;
          }
          a[r] = v;
        }
      }

      float cm = a0[0];
#pragma unroll
      for (int r = 1; r < 16; ++r) cm = fmaxf(cm, a0[r]);
#pragma unroll
      for (int r = 0; r < 16; ++r) cm = fmaxf(cm, a1[r]);
      float pm = fmaxf(cm, __shfl_xor(cm, 32));

      if (!__all(pm <= mx + 8.f)) {
        float mn = fmaxf(mx, pm);
        float fac = __builtin_amdgcn_exp2f(mx - mn);
        mx = mn;
        lsum *= fac;
#pragma unroll
        for (int r = 0; r < 16; ++r) {
          float fq = __shfl(fac, (r & 3) + 8 * (r >> 2) + 4 * hi);
          o0[r] *= fq;
          o1[r] *= fq;
        }
      }

      float rs = 0.f;
      short8 pa[4];
#pragma unroll
      for (int t = 0; t < 2; ++t) {
        f32x16& a = t ? a1 : a0;
#pragma unroll
        for (int r = 0; r < 16; ++r) {
          float e = __builtin_amdgcn_exp2f(a[r] - mx);
          a[r] = e;
          rs += e;
        }
#pragma unroll
        for (int g = 0; g < 2; ++g) {
          union { unsigned int u; __hip_bfloat162 h2; } X, X2, Y, Y2;
          X.h2 = __float22bfloat162_rn(float2{a[g * 8 + 0], a[g * 8 + 1]});
          X2.h2 = __float22bfloat162_rn(float2{a[g * 8 + 2], a[g * 8 + 3]});
          Y.h2 = __float22bfloat162_rn(float2{a[g * 8 + 4], a[g * 8 + 5]});
          Y2.h2 = __float22bfloat162_rn(float2{a[g * 8 + 6], a[g * 8 + 7]});
          asm volatile("v_permlane32_swap_b32 %0, %1" : "+v"(X.u), "+v"(Y.u));
          asm volatile("v_permlane32_swap_b32 %0, %1" : "+v"(X2.u), "+v"(Y2.u));
          union { unsigned int u[4]; short8 s; } P;
          P.u[0] = X.u;
          P.u[1] = X2.u;
          P.u[2] = Y.u;
          P.u[3] = Y2.u;
          pa[t * 2 + g] = P.s;
        }
      }
      lsum += rs + __shfl_xor(rs, 32);

#pragma unroll
      for (int ks = 0; ks < 4; ++ks) {
        const int vcol = (ks * 16 + hi * 8) ^ rsw;
        short8 vf0 = *reinterpret_cast<const short8*>(&Vs[cur][q * 64 + vcol]);
        short8 vf1 = *reinterpret_cast<const short8*>(&Vs[cur][(32 + q) * 64 + vcol]);
        o0 = __builtin_amdgcn_mfma_f32_32x32x16_bf16(pa[ks], vf0, o0, 0, 0, 0);
        o1 = __builtin_amdgcn_mfma_f32_32x32x16_bf16(pa[ks], vf1, o1, 0, 0, 0);
      }
    }

    if (c + 1 < c1) stage(cur ^ 1);
    __syncthreads();
  }

  if (mode == 0) {
    float inv = 1.0f / lsum;
#pragma unroll
    for (int r = 0; r < 16; ++r) {
      const int crow = (r & 3) + 8 * (r >> 2) + 4 * hi;
      float iq = __shfl(inv, crow);
      size_t base = (size_t)(b * NS + qw + crow) * ND + h * NHD;
      AO[base + q] = __float2bfloat16(o0[r] * iq);
      AO[base + 32 + q] = __float2bfloat16(o1[r] * iq);
    }
  } else {
    const int ps = (tile - 8) * 2 + (mode - 1);
    float* Ob = Opart + ((size_t)(ps * 32 + bh) * 128) * 64;
    if (hi == 0) ML[(ps * 32 + bh) * 128 + w * 32 + q] = float2{mx, lsum};
#pragma unroll
    for (int r = 0; r < 16; ++r) {
      const int crow = (r & 3) + 8 * (r >> 2) + 4 * hi;
      Ob[(w * 32 + crow) * 64 + q] = o0[r];
      Ob[(w * 32 + crow) * 64 + 32 + q] = o1[r];
    }
  }
}

// ---------------- split-K combine: LSE merge of part0/part1 -> AO (R16 verified) --------
__global__ __launch_bounds__(256) void combine_kernel(const float* __restrict__ Opart,
                                                      const float2* __restrict__ ML,
                                                      bf16* __restrict__ AO) {
  const int unit = blockIdx.x;  // 0..255
  const int t8 = unit >> 5, bh = unit & 31;
  const int tile = 8 + t8;
  const int b = bh >> 4, h = bh & 15;
  const int ps0 = t8 * 2, ps1 = t8 * 2 + 1;
  const int row = threadIdx.x >> 1;
  const int ch = (threadIdx.x & 1) * 32;
  float2 ml0 = ML[(ps0 * 32 + bh) * 128 + row];
  float2 ml1 = ML[(ps1 * 32 + bh) * 128 + row];
  float m = fmaxf(ml0.x, ml1.x);
  float s0 = exp2f(ml0.x - m), s1 = exp2f(ml1.x - m);
  float invl = 1.0f / (ml0.y * s0 + ml1.y * s1);
  s0 *= invl;
  s1 *= invl;
  const float* O0 = Opart + ((size_t)(ps0 * 32 + bh) * 128 + row) * 64 + ch;
  const float* O1 = Opart + ((size_t)(ps1 * 32 + bh) * 128 + row) * 64 + ch;
  bf16* dst = AO + (size_t)(b * NS + tile * 128 + row) * ND + h * NHD + ch;
#pragma unroll
  for (int g = 0; g < 4; ++g) {
    float4 a0 = *reinterpret_cast<const float4*>(O0 + g * 8);
    float4 a1 = *reinterpret_cast<const float4*>(O0 + g * 8 + 4);
    float4 c0 = *reinterpret_cast<const float4*>(O1 + g * 8);
    float4 c1 = *reinterpret_cast<const float4*>(O1 + g * 8 + 4);
    alignas(16) bf16 rr[8];
    rr[0] = __float2bfloat16(a0.x * s0 + c0.x * s1);
    rr[1] = __float2bfloat16(a0.y * s0 + c0.y * s1);
    rr[2] = __float2bfloat16(a0.z * s0 + c0.z * s1);
    rr[3] = __float2bfloat16(a0.w * s0 + c0.w * s1);
    rr[4] = __float2bfloat16(a1.x * s0 + c1.x * s1);
    rr[5] = __float2bfloat16(a1.y * s0 + c1.y * s1);
    rr[6] = __float2bfloat16(a1.z * s0 + c1.z * s1);
    rr[7] = __float2bfloat16(a1.w * s0 + c1.w * s1);
    *reinterpret_cast<short8*>(dst + g * 8) = *reinterpret_cast<const short8*>(rr);
  }
}

extern "C" void kernel_launch(void* const* d_in, const int* in_sizes, int n_in,
                              void* d_out, int out_size, void* d_ws, size_t ws_size,
                              hipStream_t stream) {
  const float* x = (const float*)d_in[0];
  const int* amask = (const int*)d_in[1];
  const float* Wqkv = (const float*)d_in[2];
  const float* Wout = (const float*)d_in[3];
  float* out = (float*)d_out;

  char* p = (char*)d_ws;
  bf16* xb = (bf16*)(p);                  // 8,388,608
  bf16* wqkvb = (bf16*)(p + 8388608);     // 6,291,456 (dead after gemm_qkv)
  bf16* woutb = (bf16*)(p + 14680064);    // 2,097,152 -> 16,777,216
  float* mbias = (float*)(p + 16777216);  // 16,384
  float2* ML = (float2*)(p + 16793600);   // 524,288 -> 17,317,888
  float* cs_tab = (float*)(p + 25165824); // 262,144 (live only during gemm_qkv)
  float* sn_tab = (float*)(p + 25427968); // 262,144 (live only during gemm_qkv)
  float* Opart = (float*)(p + 25165824);  // 16,777,216 -> 41,943,040 (after gemm_qkv)
  bf16* Qr = (bf16*)(p + 41943040);       // 8,388,608
  bf16* Kr = (bf16*)(p + 50331648);       // 8,388,608
  bf16* Vt = (bf16*)(p + 58720256);       // 8,388,608 -> 67,108,864 end
  bf16* AO = xb;                          // aliases xb (dead after gemm_qkv)

  prelude_kernel<<<8464, 256, 0, stream>>>((const float4*)x, xb, (const float4*)Wqkv, wqkvb,
                                           (const float4*)Wout, woutb, cs_tab, sn_tab,
                                           amask, mbias);
  gemm_qkv<<<256, 512, 0, stream>>>(xb, wqkvb, cs_tab, sn_tab, Qr, Kr, Vt);
  attn_kernel<<<768, 256, 0, stream>>>(Qr, Kr, Vt, mbias, AO, Opart, ML);
  combine_kernel<<<256, 256, 0, stream>>>(Opart, ML, AO);
  gemm_bt<<<256, 512, 0, stream>>>(AO, woutb, out);
}

// Round 19
// 109.576 us; speedup vs baseline: 1.1822x; 1.0317x over previous
//
#include <hip/hip_runtime.h>
#include <hip/hip_bf16.h>
#include <math.h>
#include <stdint.h>

typedef __hip_bfloat16 bf16;
typedef __attribute__((ext_vector_type(8))) short short8;
typedef __attribute__((ext_vector_type(4))) float f32x4;
typedef __attribute__((ext_vector_type(16))) float f32x16;

#define NB 2
#define NS 2048
#define ND 1024
#define NH 16
#define NHD 64
#define N3D 3072

// softmax scale folded into exp2 domain: (1/sqrt(64)) * log2(e)
#define SM_SCALE 0.18033688011112042f

// split-K slot table (R16 verified): 24 slots/bh, LPT order.
__constant__ const unsigned char SLOT_TILE[24] = {15, 15, 7, 14, 14, 13, 13, 6,
                                                  12, 12, 11, 11, 5, 10, 10, 9,
                                                  9,  4,  8,  8,  3, 2,  1,  0};
__constant__ const unsigned char SLOT_MODE[24] = {1, 2, 0, 1, 2, 1, 2, 0, 1, 2, 1, 2,
                                                  0, 1, 2, 1, 2, 0, 1, 2, 0, 0, 0, 0};

// ---------------- async global->LDS, 16B per lane ----------------
__device__ __forceinline__ void gload16(const bf16* g, void* l) {
  __builtin_amdgcn_global_load_lds(
      (const __attribute__((address_space(1))) uint32_t*)g,
      (__attribute__((address_space(3))) uint32_t*)l, 16, 0, 0);
}

// ---------------- fused prelude: casts + rope tables + mask bias (R18 verified) ---------
__global__ void prelude_kernel(const float4* __restrict__ x, bf16* __restrict__ xb,
                               const float4* __restrict__ wq, bf16* __restrict__ wqb,
                               const float4* __restrict__ wo, bf16* __restrict__ wob,
                               float* __restrict__ cs_tab, float* __restrict__ sn_tab,
                               const int* __restrict__ amask, float* __restrict__ mbias) {
  const int blk = blockIdx.x;
  if (blk < 8192) {
    int i = blk * 256 + threadIdx.x;
    const float4* src;
    bf16* dst;
    int off;
    if (i < 1048576) {
      src = x; dst = xb; off = i;
    } else if (i < 1835008) {
      src = wq; dst = wqb; off = i - 1048576;
    } else {
      src = wo; dst = wob; off = i - 1835008;
    }
    float4 v = src[off];
    alignas(8) bf16 r[4];
    r[0] = __float2bfloat16(v.x);
    r[1] = __float2bfloat16(v.y);
    r[2] = __float2bfloat16(v.z);
    r[3] = __float2bfloat16(v.w);
    *reinterpret_cast<uint2*>(dst + (size_t)off * 4) = *reinterpret_cast<const uint2*>(r);
  } else if (blk < 8448) {
    int idx = (blk - 8192) * 256 + threadIdx.x;  // 65536
    int j = idx & 31;
    int s = idx >> 5;
    float inv = exp2f((float)(2 * j) * (-13.287712379549449f / 64.0f));
    float ang = (float)s * inv;
    float sn, cs;
    sincosf(ang, &sn, &cs);
    cs_tab[idx] = cs;
    sn_tab[idx] = sn;
  } else {
    int i = (blk - 8448) * 256 + threadIdx.x;  // 4096
    mbias[i] = amask[i] ? 0.f : -1e30f;
  }
}

// ========== persistent 3-tile QKV GEMM (R15 verified; R19: 8byy x 4g XCD rect) ==========
__global__ __launch_bounds__(512) void gemm_qkv(const bf16* __restrict__ Ap,
                                                const bf16* __restrict__ Bp,
                                                const float* __restrict__ cs_tab,
                                                const float* __restrict__ sn_tab,
                                                bf16* __restrict__ Qr, bf16* __restrict__ Kr,
                                                bf16* __restrict__ Vt) {
  __shared__ short L[2][32768];  // [slot][A|B0|B1|B2], each region [128][64]
  const int tid = threadIdx.x;
  const int lane = tid & 63;
  const int w = tid >> 6;
  const int wm = w >> 2, wn = w & 3;
  const int l15 = lane & 15, l4 = lane >> 4;
  const int lin = blockIdx.x;
  const int xcd = lin & 7, t2 = lin >> 3;  // t2: 0..31
  // R19 remap: each XCD owns 8 byy x 4 g (unique set 5MB vs 7MB)
  const int byy = (xcd >> 1) * 8 + (t2 & 7);
  const int g = (xcd & 1) * 4 + (t2 >> 3);
  const int bm0 = byy * 128;
  const int bn0 = g * 128;

  const int rw = lane >> 3, sg = lane & 7;
  const int swseg = (sg ^ rw) * 8;
  const int reg = w >> 1;
  const int rowb = (w & 1) * 64 + rw;
  const bf16* srcbase;
  if (reg == 0)
    srcbase = Ap + (size_t)(bm0 + rowb) * 1024 + swseg;
  else
    srcbase = Bp + (size_t)((reg - 1) * 1024 + bn0 + rowb) * 1024 + swseg;
  const int ldsb = w * 4096;

  f32x4 acc[3][4][2] = {};

  auto issue = [&](int t) {
    short* dst = &L[t & 1][ldsb];
    const bf16* s = srcbase + t * 64;
#pragma unroll
    for (int j = 0; j < 8; ++j) gload16(s + (size_t)j * 8 * 1024, dst + j * 512);
  };

  issue(0);
  asm volatile("s_waitcnt vmcnt(0)" ::: "memory");
  __builtin_amdgcn_s_barrier();

  for (int t = 0; t < 16; ++t) {
    const short* S = L[t & 1];
    if (t + 1 < 16) issue(t + 1);
#pragma unroll
    for (int kk = 0; kk < 2; ++kk) {
      short8 af[4];
#pragma unroll
      for (int mi = 0; mi < 4; ++mi) {
        int row = wm * 64 + mi * 16 + l15;
        af[mi] = *(const short8*)&S[row * 64 + (((kk * 4 + l4) ^ (row & 7)) << 3)];
      }
#pragma unroll
      for (int tt = 0; tt < 3; ++tt) {
        short8 bfr[2];
#pragma unroll
        for (int ni = 0; ni < 2; ++ni) {
          int row = (wn >> 1) * 64 + (wn & 1) * 16 + ni * 32 + l15;
          bfr[ni] = *(const short8*)&S[(1 + tt) * 8192 + row * 64 +
                                       (((kk * 4 + l4) ^ (row & 7)) << 3)];
        }
        __builtin_amdgcn_s_setprio(1);
#pragma unroll
        for (int mi = 0; mi < 4; ++mi)
#pragma unroll
          for (int ni = 0; ni < 2; ++ni)
            acc[tt][mi][ni] = __builtin_amdgcn_mfma_f32_16x16x32_bf16(
                af[mi], bfr[ni], acc[tt][mi][ni], 0, 0, 0);
        __builtin_amdgcn_s_setprio(0);
      }
    }
    if (t + 1 < 16) {
      asm volatile("s_waitcnt vmcnt(0)" ::: "memory");
      __builtin_amdgcn_s_barrier();
    }
  }

  {
    const int j = (wn & 1) * 16 + l15;
    const int hq = g * 2 + (wn >> 1);
#pragma unroll
    for (int tt = 0; tt < 2; ++tt) {
      bf16* dst = tt ? Kr : Qr;
#pragma unroll
      for (int mi = 0; mi < 4; ++mi)
#pragma unroll
        for (int r = 0; r < 4; ++r) {
          int row = bm0 + wm * 64 + mi * 16 + l4 * 4 + r;
          int b = row >> 11;
          int s = row & (NS - 1);
          float cs = cs_tab[s * 32 + j];
          float sn = sn_tab[s * 32 + j];
          float v0 = acc[tt][mi][0][r];
          float v1 = acc[tt][mi][1][r];
          size_t base = ((size_t)(b * NH + hq) * NS + s) * NHD + j;
          dst[base] = __float2bfloat16(v0 * cs - v1 * sn);
          dst[base + 32] = __float2bfloat16(v1 * cs + v0 * sn);
        }
    }
  }
  __syncthreads();
  {
    bf16* vtile = reinterpret_cast<bf16*>(&L[0][0]);  // [128 c][136 s]
#pragma unroll
    for (int mi = 0; mi < 4; ++mi)
#pragma unroll
      for (int ni = 0; ni < 2; ++ni)
#pragma unroll
        for (int r = 0; r < 4; ++r) {
          int srow = wm * 64 + mi * 16 + l4 * 4 + r;
          int c = (wn >> 1) * 64 + (wn & 1) * 16 + ni * 32 + l15;
          vtile[c * 136 + srow] = __float2bfloat16(acc[2][mi][ni][r]);
        }
    __syncthreads();
    const int b_ = bm0 >> 11;
    const int s0 = (bm0 & (NS - 1)) + (tid & 3) * 32;
    const int c = tid >> 2;
    const int head = g * 2 + (c >> 6);
    bf16* dstp = Vt + (((size_t)(b_ * NH + head)) * NHD + (c & 63)) * NS + s0;
#pragma unroll
    for (int gg = 0; gg < 4; ++gg)
      *reinterpret_cast<short8*>(dstp + gg * 8) =
          *reinterpret_cast<const short8*>(&vtile[c * 136 + (tid & 3) * 32 + gg * 8]);
  }
}

// ================= pipelined GEMM core (round-10 verified, R14 1-barrier/iter) ==========
#define GEMM_PIPE_BODY(...)                                                               \
  __shared__ short As[3][128 * 64];                                                       \
  __shared__ short Bs[3][128 * 64];                                                       \
  const int tid = threadIdx.x;                                                            \
  const int lane = tid & 63;                                                              \
  const int w = tid >> 6;                                                                 \
  const int wm = w >> 2, wn = w & 3;                                                      \
  const int l15 = lane & 15, l4 = lane >> 4;                                              \
  const int r0 = tid >> 3, seg = tid & 7;                                                 \
  const int sw = ((seg ^ (r0 & 7)) << 3);                                                 \
  const bf16* Ar0 = Ap + (size_t)(bm0 + r0) * 1024 + sw;                                  \
  const bf16* Ar1 = Ap + (size_t)(bm0 + r0 + 64) * 1024 + sw;                             \
  const bf16* Br0 = Bp + (size_t)(bn0 + r0) * 1024 + sw;                                  \
  const bf16* Br1 = Bp + (size_t)(bn0 + r0 + 64) * 1024 + sw;                             \
  f32x4 acc[4][2] = {};                                                                   \
  gload16(Ar0 + 0, &As[0][w * 512]);                                                      \
  gload16(Ar1 + 0, &As[0][4096 + w * 512]);                                               \
  gload16(Br0 + 0, &Bs[0][w * 512]);                                                      \
  gload16(Br1 + 0, &Bs[0][4096 + w * 512]);                                               \
  gload16(Ar0 + 64, &As[1][w * 512]);                                                     \
  gload16(Ar1 + 64, &As[1][4096 + w * 512]);                                              \
  gload16(Br0 + 64, &Bs[1][w * 512]);                                                     \
  gload16(Br1 + 64, &Bs[1][4096 + w * 512]);                                              \
  asm volatile("s_waitcnt vmcnt(4)" ::: "memory");                                        \
  __builtin_amdgcn_s_barrier();                                                           \
  for (int t = 0; t < 16; ++t) {                                                          \
    const int slot = t % 3;                                                               \
    if (t + 2 < 16) {                                                                     \
      const int ns = (t + 2) % 3;                                                         \
      const int nk = (t + 2) * 64;                                                        \
      gload16(Ar0 + nk, &As[ns][w * 512]);                                                \
      gload16(Ar1 + nk, &As[ns][4096 + w * 512]);                                         \
      gload16(Br0 + nk, &Bs[ns][w * 512]);                                                \
      gload16(Br1 + nk, &Bs[ns][4096 + w * 512]);                                         \
    }                                                                                     \
    _Pragma("unroll") for (int kk = 0; kk < 2; ++kk) {                                    \
      short8 af[4], bfr[2];                                                               \
      _Pragma("unroll") for (int mi = 0; mi < 4; ++mi) {                                  \
        int row = wm * 64 + mi * 16 + l15;                                                \
        af[mi] = *(const short8*)&As[slot][row * 64 + (((kk * 4 + l4) ^ (row & 7)) << 3)];\
      }                                                                                   \
      _Pragma("unroll") for (int ni = 0; ni < 2; ++ni) {                                  \
        int row = (wn >> 1) * 64 + (wn & 1) * 16 + ni * 32 + l15;                         \
        bfr[ni] = *(const short8*)&Bs[slot][row * 64 + (((kk * 4 + l4) ^ (row & 7)) << 3)];\
      }                                                                                   \
      __builtin_amdgcn_s_setprio(1);                                                      \
      _Pragma("unroll") for (int mi = 0; mi < 4; ++mi)                                    \
        _Pragma("unroll") for (int ni = 0; ni < 2; ++ni)                                  \
          acc[mi][ni] =                                                                   \
              __builtin_amdgcn_mfma_f32_16x16x32_bf16(af[mi], bfr[ni], acc[mi][ni], 0, 0, 0);\
      __builtin_amdgcn_s_setprio(0);                                                      \
    }                                                                                     \
    if (t + 2 < 16) {                                                                     \
      asm volatile("s_waitcnt vmcnt(4)" ::: "memory");                                    \
      __builtin_amdgcn_s_barrier();                                                       \
    } else if (t < 15) {                                                                  \
      asm volatile("s_waitcnt vmcnt(0)" ::: "memory");                                    \
      __builtin_amdgcn_s_barrier();                                                       \
    }                                                                                     \
  }                                                                                       \
  __VA_ARGS__

// ---------------- out-proj GEMM, M=4096 N=1024 K=1024, fp32 out ----------------
__global__ __launch_bounds__(512) void gemm_bt(const bf16* __restrict__ Ap,
                                               const bf16* __restrict__ Bp,
                                               float* __restrict__ Cv) {
  const int lin = blockIdx.x;
  const int xcd = lin & 7, idx = lin >> 3;  // 0..31
  const int bxx = (xcd & 1) * 4 + (idx & 3);
  const int byy = (xcd >> 1) * 8 + (idx >> 2);
  const int bn0 = bxx * 128, bm0 = byy * 128;
  GEMM_PIPE_BODY(
    _Pragma("unroll") for (int mi = 0; mi < 4; ++mi) {
      _Pragma("unroll") for (int ni = 0; ni < 2; ++ni) {
        _Pragma("unroll") for (int r = 0; r < 4; ++r) {
          int row = bm0 + wm * 64 + mi * 16 + l4 * 4 + r;
          int col = bn0 + (wn >> 1) * 64 + (wn & 1) * 16 + ni * 32 + l15;
          Cv[(size_t)row * ND + col] = acc[mi][ni][r];
        }
      }
    }
  )
}

// ---------------- causal flash attention, split-K over long tiles ----------------
// R16 structure; R19: partial parts write NORMALIZED bf16 O + f32 (m,l).
__global__ __launch_bounds__(256, 2) void attn_kernel(const bf16* __restrict__ Qr,
                                                      const bf16* __restrict__ Kr,
                                                      const bf16* __restrict__ Vt,
                                                      const float* __restrict__ mb,
                                                      bf16* __restrict__ AO,
                                                      bf16* __restrict__ Opart,
                                                      float2* __restrict__ ML) {
  __shared__ short Ks[2][64 * 64];
  __shared__ short Vs[2][64 * 64];
  __shared__ float Mb[2][64];

  const int tid = threadIdx.x;
  const int lane = tid & 63;
  const int w = tid >> 6;
  const int q = lane & 31;
  const int hi = lane >> 5;

  const int lin = blockIdx.x;
  const int xcd = lin & 7;
  const int k = lin >> 3;           // 0..95
  const int bh = xcd * 4 + (k & 3);
  const int slot = k >> 2;          // 0..23
  const int tile = SLOT_TILE[slot];
  const int mode = SLOT_MODE[slot];
  const int b = bh >> 4, h = bh & 15;
  const int qw = tile * 128 + w * 32;
  const int c0 = (mode == 2) ? tile + 1 : 0;
  const int c1 = (mode == 1) ? tile + 1 : 2 * tile + 2;

  const bf16* Qb = Qr + (size_t)bh * NS * NHD;
  const bf16* Kb = Kr + (size_t)bh * NS * NHD;
  const bf16* Vb = Vt + (size_t)bh * NHD * NS;

  const int srow = tid >> 2;
  const int sc0 = (tid & 3) * 16;
  const int swz = (srow & 7) << 3;

  short8 Qf[4];
#pragma unroll
  for (int s = 0; s < 4; ++s)
    Qf[s] = *reinterpret_cast<const short8*>(&Qb[(size_t)(qw + q) * NHD + s * 16 + hi * 8]);

  f32x16 o0 = {}, o1 = {};
  float mx = -1e30f, lsum = 0.f;

  short8 kreg[2], vreg[2];
  float4 mreg;
  auto prefetch = [&](int kv0) {
    kreg[0] = *reinterpret_cast<const short8*>(&Kb[(size_t)(kv0 + srow) * NHD + sc0]);
    kreg[1] = *reinterpret_cast<const short8*>(&Kb[(size_t)(kv0 + srow) * NHD + sc0 + 8]);
    vreg[0] = *reinterpret_cast<const short8*>(&Vb[(size_t)srow * NS + kv0 + sc0]);
    vreg[1] = *reinterpret_cast<const short8*>(&Vb[(size_t)srow * NS + kv0 + sc0 + 8]);
    if (tid < 16) mreg = *reinterpret_cast<const float4*>(&mb[b * NS + kv0 + tid * 4]);
  };
  auto stage = [&](int buf) {
    *reinterpret_cast<short8*>(&Ks[buf][srow * 64 + (sc0 ^ swz)]) = kreg[0];
    *reinterpret_cast<short8*>(&Ks[buf][srow * 64 + ((sc0 + 8) ^ swz)]) = kreg[1];
    *reinterpret_cast<short8*>(&Vs[buf][srow * 64 + (sc0 ^ swz)]) = vreg[0];
    *reinterpret_cast<short8*>(&Vs[buf][srow * 64 + ((sc0 + 8) ^ swz)]) = vreg[1];
    if (tid < 16) *reinterpret_cast<float4*>(&Mb[buf][tid * 4]) = mreg;
  };

  prefetch(c0 * 64);
  stage(0);
  __syncthreads();

  const int rsw = (q & 7) << 3;

  for (int c = c0; c < c1; ++c) {
    const int cur = (c - c0) & 1;
    const int kv0 = c * 64;
    if (c + 1 < c1) prefetch((c + 1) * 64);

    if (kv0 < qw + 32) {
      f32x16 a0 = {}, a1 = {};
#pragma unroll
      for (int s = 0; s < 4; ++s) {
        short8 kf0 = *reinterpret_cast<const short8*>(
            &Ks[cur][q * 64 + ((s * 16 + hi * 8) ^ rsw)]);
        short8 kf1 = *reinterpret_cast<const short8*>(
            &Ks[cur][(32 + q) * 64 + ((s * 16 + hi * 8) ^ rsw)]);
        a0 = __builtin_amdgcn_mfma_f32_32x32x16_bf16(kf0, Qf[s], a0, 0, 0, 0);
        a1 = __builtin_amdgcn_mfma_f32_32x32x16_bf16(kf1, Qf[s], a1, 0, 0, 0);
      }

      float4 bv[2][4];
#pragma unroll
      for (int t = 0; t < 2; ++t)
#pragma unroll
        for (int g = 0; g < 4; ++g)
          bv[t][g] = *reinterpret_cast<const float4*>(&Mb[cur][t * 32 + g * 8 + hi * 4]);
      const int qg = qw + q;
#pragma unroll
      for (int t = 0; t < 2; ++t) {
        f32x16& a = t ? a1 : a0;
        const bool needc = (kv0 + t * 32 + 31 > qw);
#pragma unroll
        for (int r = 0; r < 16; ++r) {
          float v = fmaf(a[r], SM_SCALE, ((const float*)&bv[t][r >> 2])[r & 3]);
          if (needc) {
            int kvg = kv0 + t * 32 + (r & 3) + 8 * (r >> 2) + 4 * hi;
            if (kvg > qg) v = -1e30f;
          }
          a[r] = v;
        }
      }

      float cm = a0[0];
#pragma unroll
      for (int r = 1; r < 16; ++r) cm = fmaxf(cm, a0[r]);
#pragma unroll
      for (int r = 0; r < 16; ++r) cm = fmaxf(cm, a1[r]);
      float pm = fmaxf(cm, __shfl_xor(cm, 32));

      if (!__all(pm <= mx + 8.f)) {
        float mn = fmaxf(mx, pm);
        float fac = __builtin_amdgcn_exp2f(mx - mn);
        mx = mn;
        lsum *= fac;
#pragma unroll
        for (int r = 0; r < 16; ++r) {
          float fq = __shfl(fac, (r & 3) + 8 * (r >> 2) + 4 * hi);
          o0[r] *= fq;
          o1[r] *= fq;
        }
      }

      float rs = 0.f;
      short8 pa[4];
#pragma unroll
      for (int t = 0; t < 2; ++t) {
        f32x16& a = t ? a1 : a0;
#pragma unroll
        for (int r = 0; r < 16; ++r) {
          float e = __builtin_amdgcn_exp2f(a[r] - mx);
          a[r] = e;
          rs += e;
        }
#pragma unroll
        for (int g = 0; g < 2; ++g) {
          union { unsigned int u; __hip_bfloat162 h2; } X, X2, Y, Y2;
          X.h2 = __float22bfloat162_rn(float2{a[g * 8 + 0], a[g * 8 + 1]});
          X2.h2 = __float22bfloat162_rn(float2{a[g * 8 + 2], a[g * 8 + 3]});
          Y.h2 = __float22bfloat162_rn(float2{a[g * 8 + 4], a[g * 8 + 5]});
          Y2.h2 = __float22bfloat162_rn(float2{a[g * 8 + 6], a[g * 8 + 7]});
          asm volatile("v_permlane32_swap_b32 %0, %1" : "+v"(X.u), "+v"(Y.u));
          asm volatile("v_permlane32_swap_b32 %0, %1" : "+v"(X2.u), "+v"(Y2.u));
          union { unsigned int u[4]; short8 s; } P;
          P.u[0] = X.u;
          P.u[1] = X2.u;
          P.u[2] = Y.u;
          P.u[3] = Y2.u;
          pa[t * 2 + g] = P.s;
        }
      }
      lsum += rs + __shfl_xor(rs, 32);

#pragma unroll
      for (int ks = 0; ks < 4; ++ks) {
        const int vcol = (ks * 16 + hi * 8) ^ rsw;
        short8 vf0 = *reinterpret_cast<const short8*>(&Vs[cur][q * 64 + vcol]);
        short8 vf1 = *reinterpret_cast<const short8*>(&Vs[cur][(32 + q) * 64 + vcol]);
        o0 = __builtin_amdgcn_mfma_f32_32x32x16_bf16(pa[ks], vf0, o0, 0, 0, 0);
        o1 = __builtin_amdgcn_mfma_f32_32x32x16_bf16(pa[ks], vf1, o1, 0, 0, 0);
      }
    }

    if (c + 1 < c1) stage(cur ^ 1);
    __syncthreads();
  }

  float inv = 1.0f / lsum;
  if (mode == 0) {
#pragma unroll
    for (int r = 0; r < 16; ++r) {
      const int crow = (r & 3) + 8 * (r >> 2) + 4 * hi;
      float iq = __shfl(inv, crow);
      size_t base = (size_t)(b * NS + qw + crow) * ND + h * NHD;
      AO[base + q] = __float2bfloat16(o0[r] * iq);
      AO[base + 32 + q] = __float2bfloat16(o1[r] * iq);
    }
  } else {
    const int ps = (tile - 8) * 2 + (mode - 1);
    bf16* Ob = Opart + ((size_t)(ps * 32 + bh) * 128) * 64;
    if (hi == 0) ML[(ps * 32 + bh) * 128 + w * 32 + q] = float2{mx, lsum};
#pragma unroll
    for (int r = 0; r < 16; ++r) {
      const int crow = (r & 3) + 8 * (r >> 2) + 4 * hi;
      float iq = __shfl(inv, crow);
      Ob[(w * 32 + crow) * 64 + q] = __float2bfloat16(o0[r] * iq);
      Ob[(w * 32 + crow) * 64 + 32 + q] = __float2bfloat16(o1[r] * iq);
    }
  }
}

// ---------------- split-K combine: weighted merge of 2 normalized bf16 parts -> AO ------
__global__ __launch_bounds__(256) void combine_kernel(const bf16* __restrict__ Opart,
                                                      const float2* __restrict__ ML,
                                                      bf16* __restrict__ AO) {
  const int unit = blockIdx.x;  // 0..255
  const int t8 = unit >> 5, bh = unit & 31;
  const int tile = 8 + t8;
  const int b = bh >> 4, h = bh & 15;
  const int ps0 = t8 * 2, ps1 = t8 * 2 + 1;
  const int row = threadIdx.x >> 1;
  const int ch = (threadIdx.x & 1) * 32;
  float2 ml0 = ML[(ps0 * 32 + bh) * 128 + row];
  float2 ml1 = ML[(ps1 * 32 + bh) * 128 + row];
  float m = fmaxf(ml0.x, ml1.x);
  float w0 = ml0.y * exp2f(ml0.x - m);
  float w1 = ml1.y * exp2f(ml1.x - m);
  float invw = 1.0f / (w0 + w1);
  w0 *= invw;
  w1 *= invw;
  const bf16* O0 = Opart + ((size_t)(ps0 * 32 + bh) * 128 + row) * 64 + ch;
  const bf16* O1 = Opart + ((size_t)(ps1 * 32 + bh) * 128 + row) * 64 + ch;
  bf16* dst = AO + (size_t)(b * NS + tile * 128 + row) * ND + h * NHD + ch;
#pragma unroll
  for (int g = 0; g < 4; ++g) {
    short8 v0 = *reinterpret_cast<const short8*>(O0 + g * 8);
    short8 v1 = *reinterpret_cast<const short8*>(O1 + g * 8);
    alignas(16) bf16 rr[8];
#pragma unroll
    for (int e = 0; e < 8; ++e) {
      float f0 = __uint_as_float(((unsigned int)(unsigned short)v0[e]) << 16);
      float f1 = __uint_as_float(((unsigned int)(unsigned short)v1[e]) << 16);
      rr[e] = __float2bfloat16(f0 * w0 + f1 * w1);
    }
    *reinterpret_cast<short8*>(dst + g * 8) = *reinterpret_cast<const short8*>(rr);
  }
}

extern "C" void kernel_launch(void* const* d_in, const int* in_sizes, int n_in,
                              void* d_out, int out_size, void* d_ws, size_t ws_size,
                              hipStream_t stream) {
  const float* x = (const float*)d_in[0];
  const int* amask = (const int*)d_in[1];
  const float* Wqkv = (const float*)d_in[2];
  const float* Wout = (const float*)d_in[3];
  float* out = (float*)d_out;

  char* p = (char*)d_ws;
  bf16* xb = (bf16*)(p);                  // 8,388,608
  bf16* wqkvb = (bf16*)(p + 8388608);     // 6,291,456 (dead after gemm_qkv)
  bf16* woutb = (bf16*)(p + 14680064);    // 2,097,152 -> 16,777,216
  float* mbias = (float*)(p + 16777216);  // 16,384
  float2* ML = (float2*)(p + 16793600);   // 524,288 -> 17,317,888
  float* cs_tab = (float*)(p + 25165824); // 262,144 (live only during gemm_qkv)
  float* sn_tab = (float*)(p + 25427968); // 262,144 (live only during gemm_qkv)
  bf16* Opart = (bf16*)(p + 25165824);    // 8,388,608 bf16 (after gemm_qkv; reuses cs/sn)
  bf16* Qr = (bf16*)(p + 41943040);       // 8,388,608
  bf16* Kr = (bf16*)(p + 50331648);       // 8,388,608
  bf16* Vt = (bf16*)(p + 58720256);       // 8,388,608 -> 67,108,864 end
  bf16* AO = xb;                          // aliases xb (dead after gemm_qkv)

  prelude_kernel<<<8464, 256, 0, stream>>>((const float4*)x, xb, (const float4*)Wqkv, wqkvb,
                                           (const float4*)Wout, woutb, cs_tab, sn_tab,
                                           amask, mbias);
  gemm_qkv<<<256, 512, 0, stream>>>(xb, wqkvb, cs_tab, sn_tab, Qr, Kr, Vt);
  attn_kernel<<<768, 256, 0, stream>>>(Qr, Kr, Vt, mbias, AO, Opart, ML);
  combine_kernel<<<256, 256, 0, stream>>>(Opart, ML, AO);
  gemm_bt<<<256, 512, 0, stream>>>(AO, woutb, out);
}